// Round 2
// baseline (279.946 us; speedup 1.0000x reference)
//
#include <hip/hip_runtime.h>
#include <hip/hip_bf16.h>
#include <math.h>

#define BB 512
#define DD 128
#define CC 100000

#define BLK_N 64
#define LDB 136                 // bf16 units; 272B row stride (same layout as prior verified kernel)

__device__ __constant__ const float COS_M  =  0.87758256189037271612f;  // cos(0.5)
__device__ __constant__ const float SIN_M  =  0.47942553860420300538f;  // sin(0.5)
__device__ __constant__ const float THRESH = -0.87758256189037271612f;  // cos(pi-0.5)
__device__ __constant__ const float MMc    =  0.23971276930210150269f;  // sin(0.5)*0.5
#define SCALE_F 64.0f
#define ALPHA_F 1.2f

typedef __attribute__((ext_vector_type(8))) short short8;
typedef __attribute__((ext_vector_type(4))) float float4v;

__device__ inline float waveReduceSum(float v) {
    #pragma unroll
    for (int off = 32; off > 0; off >>= 1)
        v += __shfl_xor(v, off, 64);
    return v;
}

// --- K1: fused feats-normalize (-> bf16 exb) + per-row a_lb (full fp32) ---
__global__ void k_prep(const float* __restrict__ feats, const float* __restrict__ w,
                       const int* __restrict__ labels,
                       __hip_bfloat16* __restrict__ exb, float* __restrict__ alb) {
    int b = blockIdx.x;
    int lane = threadIdx.x;          // 64 threads, 2 floats each
    int lab = labels[b];
    float2 f = ((const float2*)(feats + b * DD))[lane];
    float2 g = ((const float2*)(w + (size_t)lab * DD))[lane];
    float nf  = waveReduceSum(f.x * f.x + f.y * f.y);
    float dot = waveReduceSum(f.x * g.x + f.y * g.y);
    float nw  = waveReduceSum(g.x * g.x + g.y * g.y);
    float rn = rsqrtf(nf);
    __hip_bfloat162 o;
    o.x = __float2bfloat16(f.x * rn);
    o.y = __float2bfloat16(f.y * rn);
    ((__hip_bfloat162*)(exb + b * DD))[lane] = o;
    if (lane == 0) {
        float c = dot * rsqrtf(nf * nw);
        float a;
        if (c > THRESH) {
            float cc = fminf(fmaxf(c, -1.0f), 1.0f);
            a = cc * COS_M - SIN_M * sqrtf(fmaxf(0.0f, 1.0f - cc * cc));  // cos(acos+M)
        } else {
            a = c - MMc;
        }
        alb[b] = a;
    }
}

// --- K2: zero-barrier column-tile kernel, 64 cols per block ---
// 1563 blocks, 256 threads (4 waves). LDS = Bs only (17,408 B).
// Phase 1: normalize this block's 64 weight rows f32->bf16 into LDS (each
// weight row read from HBM exactly once). ONE __syncthreads.
// Phase 2: operand-SWAPPED MFMA: D[class][batch] = mfma(class_frag, batch_frag).
//   - class fragments: loop-invariant, hoisted to 64 VGPRs (read Bs once).
//   - batch fragments: read directly from global exb (131 KB, L2-resident) --
//     no A staging, no transpose, no per-iteration barriers.
//   - acc layout: col=lane&15 -> batch row bt*16+lrow; row=(lane>>4)*4+reg ->
//     classes mt*16+lquad*4+{0..3}: each reg-quad is a contiguous float4 of
//     out[b][c..c+3] -> fused epilogue + nontemporal float4 store from regs.
// Each wave free-runs over its 8 batch row-tiles (128 rows x 64 classes).
__global__ __launch_bounds__(256, 4)
void k_main(const __hip_bfloat16* __restrict__ exb,
            const float* __restrict__ w,
            const float* __restrict__ alb,
            const int* __restrict__ labels,
            float* __restrict__ out) {
    __shared__ __align__(16) __hip_bfloat16 Bs[BLK_N][LDB];   // 17,408 B

    int tid = threadIdx.x;
    int c0 = blockIdx.x * BLK_N;

    // ---- normalize BLK_N weight rows into Bs (4 threads per row) ----
    {
        int r = tid >> 2;            // 0..63
        int h = tid & 3;             // quarter-row: 32 floats
        int c = c0 + r;
        float4 buf[8];
        float ss = 0.f;
        if (c < CC) {
            const float4* src = (const float4*)(w + (size_t)c * DD + h * 32);
            #pragma unroll
            for (int j = 0; j < 8; j++) {
                buf[j] = src[j];
                ss += buf[j].x * buf[j].x + buf[j].y * buf[j].y
                    + buf[j].z * buf[j].z + buf[j].w * buf[j].w;
            }
        } else {
            #pragma unroll
            for (int j = 0; j < 8; j++) buf[j] = make_float4(0.f, 0.f, 0.f, 0.f);
        }
        float tot = ss + __shfl_xor(ss, 1, 64);
        tot += __shfl_xor(tot, 2, 64);           // lanes 4r..4r+3 are wave-adjacent
        float rn = (c < CC) ? rsqrtf(tot) : 0.f;
        #pragma unroll
        for (int j = 0; j < 4; j++) {
            __hip_bfloat16 tmp[8];
            float4 a = buf[2 * j], b2 = buf[2 * j + 1];
            tmp[0] = __float2bfloat16(a.x * rn);
            tmp[1] = __float2bfloat16(a.y * rn);
            tmp[2] = __float2bfloat16(a.z * rn);
            tmp[3] = __float2bfloat16(a.w * rn);
            tmp[4] = __float2bfloat16(b2.x * rn);
            tmp[5] = __float2bfloat16(b2.y * rn);
            tmp[6] = __float2bfloat16(b2.z * rn);
            tmp[7] = __float2bfloat16(b2.w * rn);
            *(uint4*)(&Bs[r][h * 32 + j * 8]) = *(const uint4*)tmp;
        }
    }
    __syncthreads();   // the ONLY barrier

    int wave = tid >> 6;
    int lane = tid & 63;
    int lrow = lane & 15;
    int lquad = lane >> 4;

    // ---- hoist class fragments: cf[mt][ks] = Bs[mt*16+lrow][ks*32+lquad*8] ----
    short8 cf[4][4];
    #pragma unroll
    for (int mt = 0; mt < 4; mt++)
        #pragma unroll
        for (int ks = 0; ks < 4; ks++)
            cf[mt][ks] = *(const short8*)(&Bs[mt * 16 + lrow][ks * 32 + lquad * 8]);

    // ---- barrier-free main loop: 8 batch tiles of 16 rows per wave ----
    for (int bt = wave * 8; bt < wave * 8 + 8; ++bt) {
        int b = bt * 16 + lrow;

        // batch fragments straight from L2-resident exb: 16 rows x 64B per instr
        const short8* brow = (const short8*)(exb + (size_t)b * DD);
        short8 bfr[4];
        #pragma unroll
        for (int ks = 0; ks < 4; ks++)
            bfr[ks] = brow[ks * 4 + lquad];      // k = ks*32 + lquad*8

        float4v acc[4];
        #pragma unroll
        for (int mt = 0; mt < 4; mt++) acc[mt] = (float4v)(0.0f);

        #pragma unroll
        for (int ks = 0; ks < 4; ks++)
            #pragma unroll
            for (int mt = 0; mt < 4; mt++)
                acc[mt] = __builtin_amdgcn_mfma_f32_16x16x32_bf16(cf[mt][ks], bfr[ks], acc[mt], 0, 0, 0);

        // ---- register epilogue + direct float4 nontemporal stores ----
        // out = SCALE*( onehot*a + (1-onehot)*(rw*cos + rw - 1) ), rw = ALPHA*exp(-(cos-a)^2/2)
        float a = alb[b];
        int lab = labels[b];
        float* orow = out + (size_t)b * CC;
        #pragma unroll
        for (int mt = 0; mt < 4; mt++) {
            int cq = c0 + mt * 16 + lquad * 4;   // CC%4==0 -> whole float4 valid or invalid
            if (cq < CC) {
                float4v res;
                #pragma unroll
                for (int e = 0; e < 4; e++) {
                    float cosv = acc[mt][e];
                    float d = cosv - a;
                    float rw = ALPHA_F * __expf(-0.5f * d * d);
                    res[e] = (cq + e == lab) ? SCALE_F * a
                                             : SCALE_F * (rw * cosv + rw - 1.0f);
                }
                __builtin_nontemporal_store(res, (float4v*)(orow + cq));
            }
        }
    }
}

extern "C" void kernel_launch(void* const* d_in, const int* in_sizes, int n_in,
                              void* d_out, int out_size, void* d_ws, size_t ws_size,
                              hipStream_t stream) {
    const float* feats  = (const float*)d_in[0];
    const int*   labels = (const int*)d_in[1];
    const float* weight = (const float*)d_in[2];
    float* out = (float*)d_out;

    char* ws = (char*)d_ws;
    __hip_bfloat16* exb = (__hip_bfloat16*)ws;            // 512*128*2 = 131072 B
    float* alb = (float*)(ws + 131072);                   // 2048 B

    hipLaunchKernelGGL(k_prep, dim3(BB), dim3(64), 0, stream,
                       feats, weight, labels, exb, alb);

    dim3 grid((CC + BLK_N - 1) / BLK_N);                  // 1563 column tiles
    hipLaunchKernelGGL(k_main, grid, dim3(256), 0, stream,
                       exb, weight, alb, labels, out);
}

// Round 3
// 276.851 us; speedup vs baseline: 1.0112x; 1.0112x over previous
//
#include <hip/hip_runtime.h>
#include <hip/hip_bf16.h>
#include <math.h>

#define BB 512
#define DD 128
#define CC 100000

#define BLK_N 64
#define LDB 136                 // bf16 units; 272B row stride
#define LDT 33                  // f32 units, padded transpose row (16x32 tile per wave)

__device__ __constant__ const float COS_M  =  0.87758256189037271612f;  // cos(0.5)
__device__ __constant__ const float SIN_M  =  0.47942553860420300538f;  // sin(0.5)
__device__ __constant__ const float THRESH = -0.87758256189037271612f;  // cos(pi-0.5)
__device__ __constant__ const float MMc    =  0.23971276930210150269f;  // sin(0.5)*0.5
#define SCALE_F 64.0f
#define ALPHA_F 1.2f

typedef __attribute__((ext_vector_type(8))) short short8;
typedef __attribute__((ext_vector_type(4))) float float4v;

__device__ inline float waveReduceSum(float v) {
    #pragma unroll
    for (int off = 32; off > 0; off >>= 1)
        v += __shfl_xor(v, off, 64);
    return v;
}

// --- K1: fused feats-normalize (-> bf16 exb) + per-row a_lb (full fp32) ---
__global__ void k_prep(const float* __restrict__ feats, const float* __restrict__ w,
                       const int* __restrict__ labels,
                       __hip_bfloat16* __restrict__ exb, float* __restrict__ alb) {
    int b = blockIdx.x;
    int lane = threadIdx.x;          // 64 threads, 2 floats each
    int lab = labels[b];
    float2 f = ((const float2*)(feats + b * DD))[lane];
    float2 g = ((const float2*)(w + (size_t)lab * DD))[lane];
    float nf  = waveReduceSum(f.x * f.x + f.y * f.y);
    float dot = waveReduceSum(f.x * g.x + f.y * g.y);
    float nw  = waveReduceSum(g.x * g.x + g.y * g.y);
    float rn = rsqrtf(nf);
    __hip_bfloat162 o;
    o.x = __float2bfloat16(f.x * rn);
    o.y = __float2bfloat16(f.y * rn);
    ((__hip_bfloat162*)(exb + b * DD))[lane] = o;
    if (lane == 0) {
        float c = dot * rsqrtf(nf * nw);
        float a;
        if (c > THRESH) {
            float cc = fminf(fmaxf(c, -1.0f), 1.0f);
            a = cc * COS_M - SIN_M * sqrtf(fmaxf(0.0f, 1.0f - cc * cc));  // cos(acos+M)
        } else {
            a = c - MMc;
        }
        alb[b] = a;
    }
}

// --- K2: zero-barrier column-tile kernel, 64 cols per block ---
// 1563 blocks, 256 threads (4 waves). LDS = Bs (17,408 B) + per-wave
// transpose tiles (8,448 B) = 25,856 B -> 4 blocks/CU.
// Phase 1: normalize the block's 64 weight rows f32->bf16 into LDS.
// ONE __syncthreads, then waves free-run.
// Phase 2: operand-SWAPPED MFMA D[class][batch] = mfma(class_frag, batch_frag).
// Per wave: 32 classes (ch = wave&1) x 256 batch rows (bh = wave>>1):
//   - cf[2][4] = 32 VGPRs of hoisted class fragments (fits the 128-reg cap
//     of __launch_bounds__(256,4) with room to spare -- round-2 spilled).
//   - batch fragments straight from L2-resident exb.
//   - PER-WAVE LDS transpose (16x33 f32, same-wave ds_write->ds_read needs
//     no barrier): turns the 64B-segment store pattern of round 2 into
//     8 rows x 128B FULL-LINE nontemporal stores per instruction.
__global__ __launch_bounds__(256, 4)
void k_main(const __hip_bfloat16* __restrict__ exb,
            const float* __restrict__ w,
            const float* __restrict__ alb,
            const int* __restrict__ labels,
            float* __restrict__ out) {
    __shared__ __align__(16) __hip_bfloat16 Bs[BLK_N][LDB];   // 17,408 B
    __shared__ __align__(16) float Tt[4][16 * LDT];           //  8,448 B

    int tid = threadIdx.x;
    int c0 = blockIdx.x * BLK_N;

    // ---- normalize BLK_N weight rows into Bs (4 threads per row) ----
    {
        int r = tid >> 2;            // 0..63
        int h = tid & 3;             // quarter-row: 32 floats
        int c = c0 + r;
        float4 buf[8];
        float ss = 0.f;
        if (c < CC) {
            const float4* src = (const float4*)(w + (size_t)c * DD + h * 32);
            #pragma unroll
            for (int j = 0; j < 8; j++) {
                buf[j] = src[j];
                ss += buf[j].x * buf[j].x + buf[j].y * buf[j].y
                    + buf[j].z * buf[j].z + buf[j].w * buf[j].w;
            }
        } else {
            #pragma unroll
            for (int j = 0; j < 8; j++) buf[j] = make_float4(0.f, 0.f, 0.f, 0.f);
        }
        float tot = ss + __shfl_xor(ss, 1, 64);
        tot += __shfl_xor(tot, 2, 64);           // lanes 4r..4r+3 are wave-adjacent
        float rn = (c < CC) ? rsqrtf(tot) : 0.f;
        #pragma unroll
        for (int j = 0; j < 4; j++) {
            __hip_bfloat16 tmp[8];
            float4 a = buf[2 * j], b2 = buf[2 * j + 1];
            tmp[0] = __float2bfloat16(a.x * rn);
            tmp[1] = __float2bfloat16(a.y * rn);
            tmp[2] = __float2bfloat16(a.z * rn);
            tmp[3] = __float2bfloat16(a.w * rn);
            tmp[4] = __float2bfloat16(b2.x * rn);
            tmp[5] = __float2bfloat16(b2.y * rn);
            tmp[6] = __float2bfloat16(b2.z * rn);
            tmp[7] = __float2bfloat16(b2.w * rn);
            *(uint4*)(&Bs[r][h * 32 + j * 8]) = *(const uint4*)tmp;
        }
    }
    __syncthreads();   // the ONLY barrier

    int wave = tid >> 6;
    int lane = tid & 63;
    int lrow = lane & 15;
    int lquad = lane >> 4;
    int ch = wave & 1;               // class half: 32 classes
    int bh = wave >> 1;              // batch half: 256 rows
    float* Tw = Tt[wave];

    // ---- hoist class fragments: cf[mt][ks], classes ch*32 + mt*16 + lrow ----
    short8 cf[2][4];
    #pragma unroll
    for (int mt = 0; mt < 2; mt++)
        #pragma unroll
        for (int ks = 0; ks < 4; ks++)
            cf[mt][ks] = *(const short8*)(&Bs[ch * 32 + mt * 16 + lrow][ks * 32 + lquad * 8]);

    // ---- barrier-free main loop: 16 batch tiles of 16 rows per wave ----
    for (int bt = bh * 16; bt < bh * 16 + 16; ++bt) {
        int b = bt * 16 + lrow;

        // batch fragments from L2-resident exb
        const short8* brow = (const short8*)(exb + (size_t)b * DD);
        short8 bfr[4];
        #pragma unroll
        for (int ks = 0; ks < 4; ks++)
            bfr[ks] = brow[ks * 4 + lquad];      // k = ks*32 + lquad*8

        float4v acc[2];
        #pragma unroll
        for (int mt = 0; mt < 2; mt++) acc[mt] = (float4v)(0.0f);

        #pragma unroll
        for (int ks = 0; ks < 4; ks++)
            #pragma unroll
            for (int mt = 0; mt < 2; mt++)
                acc[mt] = __builtin_amdgcn_mfma_f32_16x16x32_bf16(cf[mt][ks], bfr[ks], acc[mt], 0, 0, 0);

        // ---- per-wave LDS transpose (no barrier: same-wave write->read) ----
        // acc element (mt,e): batch row lrow, local class mt*16 + lquad*4 + e
        #pragma unroll
        for (int mt = 0; mt < 2; mt++)
            *(float4v*)(&Tw[lrow * LDT + mt * 16 + lquad * 4]) = acc[mt];

        // ---- row-major epilogue + full-line stores ----
        // out = SCALE*( onehot*a + (1-onehot)*(rw*cos + rw - 1) ), rw = ALPHA*exp(-(cos-a)^2/2)
        #pragma unroll
        for (int i = 0; i < 2; i++) {
            int r  = i * 8 + (lane >> 3);        // local batch row 0..15
            int cq4 = lane & 7;                  // float4 index within 32-col strip
            int bb = bt * 16 + r;
            int cq = c0 + ch * 32 + cq4 * 4;
            if (cq < CC) {                       // CC%4==0 -> whole float4 valid
                float a = alb[bb];
                int lab = labels[bb];
                float4v v = *(const float4v*)(&Tw[r * LDT + ch * 0 + cq4 * 4]);
                float4v res;
                #pragma unroll
                for (int e = 0; e < 4; e++) {
                    float cosv = v[e];
                    float d = cosv - a;
                    float rw = ALPHA_F * __expf(-0.5f * d * d);
                    res[e] = (cq + e == lab) ? SCALE_F * a
                                             : SCALE_F * (rw * cosv + rw - 1.0f);
                }
                __builtin_nontemporal_store(res, (float4v*)(out + (size_t)bb * CC + cq));
            }
        }
    }
}

extern "C" void kernel_launch(void* const* d_in, const int* in_sizes, int n_in,
                              void* d_out, int out_size, void* d_ws, size_t ws_size,
                              hipStream_t stream) {
    const float* feats  = (const float*)d_in[0];
    const int*   labels = (const int*)d_in[1];
    const float* weight = (const float*)d_in[2];
    float* out = (float*)d_out;

    char* ws = (char*)d_ws;
    __hip_bfloat16* exb = (__hip_bfloat16*)ws;            // 512*128*2 = 131072 B
    float* alb = (float*)(ws + 131072);                   // 2048 B

    hipLaunchKernelGGL(k_prep, dim3(BB), dim3(64), 0, stream,
                       feats, weight, labels, exb, alb);

    dim3 grid((CC + BLK_N - 1) / BLK_N);                  // 1563 column tiles
    hipLaunchKernelGGL(k_main, grid, dim3(256), 0, stream,
                       exb, weight, alb, labels, out);
}